// Round 1
// baseline (3587.299 us; speedup 1.0000x reference)
//
#include <hip/hip_runtime.h>
#include <hip/hip_bf16.h>
#include <stdint.h>

#define RCNN_THRES 0.25f
#define YOLO_THRES 0.45f
#define NMS_THRES  0.4f

#define M_BOXES 6144
#define NWORDS  96      // 6144 / 64
#define SORT_N  8192

#define P_ELEMS  750000
#define P_BLOCKS 2930   // ceil(750000/256)
#define R_BLOCKS 1536   // 6144 rows / 4 waves per block
#define B_BLOCKS 24     // 6144 / 256

__device__ inline float wave_sum(float v) {
#pragma unroll
    for (int o = 32; o > 0; o >>= 1) v += __shfl_xor(v, o);
    return v;
}
__device__ inline float wave_max(float v) {
#pragma unroll
    for (int o = 32; o > 0; o >>= 1) v = fmaxf(v, __shfl_xor(v, o));
    return v;
}

__device__ inline float box_loss_term(float c5, float c4) {
    // s = 1/(0.5-0.45) = 20
    float a = fminf(fmaxf((c5 - YOLO_THRES) * 20.0f, 0.0f), 1.0f);
    float b = fminf(fmaxf((c4 - YOLO_THRES) * 20.0f, 0.0f), 1.0f);
    return -a * logf(1.0f - c5 + 0.01f) - b * logf(1.0f - c4 + 0.01f);
}

__device__ inline bool iou_gt(float x1a, float y1a, float x2a, float y2a, float aa,
                              float x1b, float y1b, float x2b, float y2b, float ab) {
    float iw = fmaxf(fminf(x2a, x2b) - fmaxf(x1a, x1b), 0.0f);
    float ih = fmaxf(fminf(y2a, y2b) - fmaxf(y1a, y1b), 0.0f);
    float inter = iw * ih;
    float uni = aa + ab - inter;
    return (inter / fmaxf(uni, 1e-12f)) > NMS_THRES;
}

// ---------------------------------------------------------------------------
// Kernel A: p_loss (image+patches bounds), r_loss (rcnn), b_loss + b_cnt
// ---------------------------------------------------------------------------
__global__ __launch_bounds__(256) void fused_losses(
    const float* __restrict__ img, const float* __restrict__ p0,
    const float* __restrict__ p1, const float* __restrict__ p2,
    const float* __restrict__ probs, const float* __restrict__ boxes,
    float* __restrict__ acc) {
    __shared__ float fred[8];
    const int tid = threadIdx.x, lane = tid & 63, wid = tid >> 6;
    const int bid = blockIdx.x;

    if (bid < P_BLOCKS) {
        int e = bid * 256 + tid;
        float local = 0.0f;
        if (e < P_ELEMS) {
            float v = img[e];
            int c = e / 250000;
            int rem = e - c * 250000;
            int y = rem / 500;
            int x = rem - y * 500;
            if (x >= 50 && x < 450) {
                int px = x - 50;
                if (y >= 75 && y < 125)       v += p0[c * 20000 + (y - 75) * 400 + px];
                else if (y >= 225 && y < 275) v += p1[c * 20000 + (y - 225) * 400 + px];
                else if (y >= 375 && y < 425) v += p2[c * 20000 + (y - 375) * 400 + px];
            }
            local = fmaxf(-v, 0.0f) + fmaxf(v - 1.0f, 0.0f);
        }
        local = wave_sum(local);
        if (lane == 0) fred[wid] = local;
        __syncthreads();
        if (tid == 0) atomicAdd(&acc[0], fred[0] + fred[1] + fred[2] + fred[3]);
    } else if (bid < P_BLOCKS + R_BLOCKS) {
        int row = (bid - P_BLOCKS) * 4 + wid;
        const float* pr = probs + row * 81;
        float m = pr[lane];                       // cols 0..63
        if (lane < 16) m = fmaxf(m, pr[64 + lane]);  // cols 64..79 (col 80 excluded)
        m = wave_max(m);
        float t = 0.0f;
        if (lane == 0 && m > RCNN_THRES) {
            float bp = pr[80];
            float cl = fminf(fmaxf((m - RCNN_THRES) * (1.0f / (0.3f - RCNN_THRES)), 0.0f), 1.0f);
            t = -logf(bp + 0.001f) - cl * logf(1.0f - m + 0.001f);
        }
        if (lane == 0) fred[wid] = t;
        __syncthreads();
        if (tid == 0) atomicAdd(&acc[1], fred[0] + fred[1] + fred[2] + fred[3]);
    } else {
        int i = (bid - P_BLOCKS - R_BLOCKS) * 256 + tid;
        float l = 0.0f, cnt = 0.0f;
        if (i < M_BOXES) {
            float conf = boxes[i * 6 + 4];
            if (conf > YOLO_THRES) {
                float c5 = boxes[i * 6 + 5];
                l = box_loss_term(c5, conf);
                cnt = 1.0f;
            }
        }
        l = wave_sum(l);
        cnt = wave_sum(cnt);
        if (lane == 0) { fred[wid] = l; fred[4 + wid] = cnt; }
        __syncthreads();
        if (tid == 0) {
            atomicAdd(&acc[2], fred[0] + fred[1] + fred[2] + fred[3]);
            atomicAdd(&acc[3], fred[4] + fred[5] + fred[6] + fred[7]);
        }
    }
}

// ---------------------------------------------------------------------------
// Kernel B: stable descending sort by conf (key = conf_bits<<13 | (8191-idx)),
// then gather sorted corner/area/conf/c5 SoA + valid bit-words.
// ---------------------------------------------------------------------------
__global__ __launch_bounds__(1024) void sort_boxes(
    const float* __restrict__ boxes,
    float* __restrict__ sx1, float* __restrict__ sy1,
    float* __restrict__ sx2, float* __restrict__ sy2,
    float* __restrict__ sarea, float* __restrict__ sconf, float* __restrict__ sc5,
    unsigned long long* __restrict__ Vw) {
    __shared__ unsigned long long keys[SORT_N];
    const int tid = threadIdx.x;

#pragma unroll
    for (int s = 0; s < SORT_N / 1024; ++s) {
        int p = tid + s * 1024;
        unsigned long long key = 0ull;
        if (p < M_BOXES) {
            unsigned int bits = __float_as_uint(boxes[p * 6 + 4]);
            key = ((unsigned long long)bits << 13) | (unsigned long long)(8191 - p);
        }
        keys[p] = key;
    }
    for (int k = 2; k <= SORT_N; k <<= 1) {
        for (int j = k >> 1; j > 0; j >>= 1) {
            __syncthreads();
#pragma unroll
            for (int s = 0; s < SORT_N / 2048; ++s) {   // 4096 pairs / 1024 threads
                int q = tid + s * 1024;
                int i = ((q & ~(j - 1)) << 1) | (q & (j - 1));
                int p2 = i | j;
                unsigned long long a = keys[i], b = keys[p2];
                bool up = ((i & k) == 0);
                if ((a < b) == up) { keys[i] = b; keys[p2] = a; }  // descending overall
            }
        }
    }
    __syncthreads();
#pragma unroll
    for (int s = 0; s < SORT_N / 1024; ++s) {
        int p = tid + s * 1024;
        bool validp = false;
        if (p < M_BOXES) {
            int idx = 8191 - (int)(keys[p] & 0x1FFFull);
            const float* b6 = boxes + idx * 6;
            float x = b6[0], y = b6[1], wd = b6[2], ht = b6[3];
            float conf = b6[4], c5 = b6[5];
            sx1[p] = x - wd * 0.5f;
            sx2[p] = x + wd * 0.5f;
            sy1[p] = y - ht * 0.5f;
            sy2[p] = y + ht * 0.5f;
            sarea[p] = wd * ht;
            sconf[p] = conf;
            sc5[p] = c5;
            validp = conf > YOLO_THRES;
        }
        unsigned long long bits = __ballot(validp);
        int word = (tid >> 6) + s * 16;
        if ((tid & 63) == 0 && word < NWORDS) Vw[word] = bits;
    }
}

// ---------------------------------------------------------------------------
// Kernel C: greedy NMS over sorted boxes (96 blocks of 64), then b_nms loss
// and final scalar combine. Single workgroup, 4 waves.
// ---------------------------------------------------------------------------
__global__ __launch_bounds__(256) void nms_finalize(
    const float* __restrict__ acc, const unsigned long long* __restrict__ Vw,
    const float* __restrict__ sx1, const float* __restrict__ sy1,
    const float* __restrict__ sx2, const float* __restrict__ sy2,
    const float* __restrict__ sarea, const float* __restrict__ sconf,
    const float* __restrict__ sc5, float* __restrict__ out) {
    __shared__ unsigned long long S_lds[NWORDS];   // accumulated suppression
    __shared__ unsigned long long D_lds[64];       // intra-block suppression rows
    __shared__ unsigned long long KW_lds[NWORDS];  // kept words
    __shared__ float fred[8];

    const int tid = threadIdx.x, lane = tid & 63, wid = tid >> 6;

    for (int i = tid; i < NWORDS; i += 256) S_lds[i] = 0ull;
    __syncthreads();

    for (int w = 0; w < NWORDS; ++w) {
        unsigned long long cur = Vw[w] & ~S_lds[w];   // uniform across block
        if (cur == 0ull) {                            // fully invalid/suppressed block
            if (tid == 0) KW_lds[w] = 0ull;
            continue;
        }
        // per-lane box of this block
        int jb = w * 64 + lane;
        float bx1 = sx1[jb], by1 = sy1[jb], bx2 = sx2[jb], by2 = sy2[jb], bar = sarea[jb];

        // D-phase: wave `wid` builds rows t = 4r + wid (only candidate rows)
#pragma unroll
        for (int r = 0; r < 16; ++r) {
            int t = r * 4 + wid;
            unsigned long long dw = 0ull;
            if ((cur >> t) & 1ull) {
                float rx1 = __shfl(bx1, t), ry1 = __shfl(by1, t);
                float rx2 = __shfl(bx2, t), ry2 = __shfl(by2, t);
                float ra  = __shfl(bar, t);
                bool pred = (lane > t) &&
                            iou_gt(rx1, ry1, rx2, ry2, ra, bx1, by1, bx2, by2, bar);
                dw = __ballot(pred);
            }
            if (lane == 0) D_lds[t] = dw;
        }
        __syncthreads();

        // greedy recurrence over 64 rows (redundant per wave; uniform word)
#pragma unroll
        for (int t = 0; t < 64; ++t) {
            unsigned long long d = D_lds[t];
            cur &= ((cur >> t) & 1ull) ? ~d : ~0ull;
        }
        if (tid == 0) KW_lds[w] = cur;

        // suppress later words for each kept row in this block
        unsigned long long kk = cur;
        while (kk) {
            int t = __builtin_ctzll(kk);
            kk &= kk - 1;
            float rx1 = __shfl(bx1, t), ry1 = __shfl(by1, t);
            float rx2 = __shfl(bx2, t), ry2 = __shfl(by2, t);
            float ra  = __shfl(bar, t);
            for (int l = w + 1 + wid; l < NWORDS; l += 4) {
                int j = l * 64 + lane;
                bool pred = iou_gt(rx1, ry1, rx2, ry2, ra,
                                   sx1[j], sy1[j], sx2[j], sy2[j], sarea[j]);
                unsigned long long bits = __ballot(pred);
                if (lane == 0) S_lds[l] |= bits;
            }
        }
        __syncthreads();
    }
    __syncthreads();

    // b_nms_loss / b_nms_cnt over kept boxes
    float nl = 0.0f, nc = 0.0f;
    for (int p = tid; p < M_BOXES; p += 256) {
        if ((KW_lds[p >> 6] >> (p & 63)) & 1ull) {
            nl += box_loss_term(sc5[p], sconf[p]);
            nc += 1.0f;
        }
    }
    nl = wave_sum(nl);
    nc = wave_sum(nc);
    if (lane == 0) { fred[wid] = nl; fred[4 + wid] = nc; }
    __syncthreads();
    if (tid == 0) {
        float tnl = fred[0] + fred[1] + fred[2] + fred[3];
        float tnc = fred[4] + fred[5] + fred[6] + fred[7];
        float p_loss = acc[0], r_loss = acc[1], b_loss = acc[2], b_cnt = acc[3];
        float yolo = b_loss + tnl * (b_cnt / fmaxf(tnc, 1.0f));
        out[0] = r_loss * 0.8f + yolo + p_loss;
    }
}

// ---------------------------------------------------------------------------
extern "C" void kernel_launch(void* const* d_in, const int* in_sizes, int n_in,
                              void* d_out, int out_size, void* d_ws, size_t ws_size,
                              hipStream_t stream) {
    const float* img   = (const float*)d_in[0];
    const float* p0    = (const float*)d_in[1];
    const float* p1    = (const float*)d_in[2];
    const float* p2    = (const float*)d_in[3];
    const float* probs = (const float*)d_in[4];
    const float* boxes = (const float*)d_in[5];
    float* out = (float*)d_out;

    char* ws = (char*)d_ws;
    float* acc = (float*)ws;                                  // 8 floats @ 0
    unsigned long long* Vw = (unsigned long long*)(ws + 64);  // 96 words
    float* sx1 = (float*)(ws + 1024);
    float* sy1 = sx1 + M_BOXES;
    float* sx2 = sy1 + M_BOXES;
    float* sy2 = sx2 + M_BOXES;
    float* sarea = sy2 + M_BOXES;
    float* sconf = sarea + M_BOXES;
    float* sc5 = sconf + M_BOXES;

    hipMemsetAsync(acc, 0, 64, stream);
    fused_losses<<<P_BLOCKS + R_BLOCKS + B_BLOCKS, 256, 0, stream>>>(
        img, p0, p1, p2, probs, boxes, acc);
    sort_boxes<<<1, 1024, 0, stream>>>(boxes, sx1, sy1, sx2, sy2, sarea, sconf, sc5, Vw);
    nms_finalize<<<1, 256, 0, stream>>>(acc, Vw, sx1, sy1, sx2, sy2, sarea, sconf, sc5, out);
}

// Round 2
// 563.871 us; speedup vs baseline: 6.3619x; 6.3619x over previous
//
#include <hip/hip_runtime.h>
#include <hip/hip_bf16.h>
#include <stdint.h>

#define RCNN_THRES 0.25f
#define YOLO_THRES 0.45f
#define NMS_THRES  0.4f

#define M_BOXES 6144
#define NWORDS  96      // 6144 / 64
#define SORT_N  8192

#define P_ELEMS  750000
#define P_BLOCKS 2930   // ceil(750000/256)
#define R_BLOCKS 1536   // 6144 rows / 4 waves per block
#define B_BLOCKS 24     // 6144 / 256
#define MB_BLOCKS 1536  // mask build: 6144 rows / 4 waves per block

__device__ inline float wave_sum(float v) {
#pragma unroll
    for (int o = 32; o > 0; o >>= 1) v += __shfl_xor(v, o);
    return v;
}
__device__ inline float wave_max(float v) {
#pragma unroll
    for (int o = 32; o > 0; o >>= 1) v = fmaxf(v, __shfl_xor(v, o));
    return v;
}

__device__ inline float box_loss_term(float c5, float c4) {
    // s = 1/(0.5-0.45) = 20
    float a = fminf(fmaxf((c5 - YOLO_THRES) * 20.0f, 0.0f), 1.0f);
    float b = fminf(fmaxf((c4 - YOLO_THRES) * 20.0f, 0.0f), 1.0f);
    return -a * logf(1.0f - c5 + 0.01f) - b * logf(1.0f - c4 + 0.01f);
}

__device__ inline bool iou_gt(float x1a, float y1a, float x2a, float y2a, float aa,
                              float x1b, float y1b, float x2b, float y2b, float ab) {
    float iw = fmaxf(fminf(x2a, x2b) - fmaxf(x1a, x1b), 0.0f);
    float ih = fmaxf(fminf(y2a, y2b) - fmaxf(y1a, y1b), 0.0f);
    float inter = iw * ih;
    float uni = aa + ab - inter;
    return (inter / fmaxf(uni, 1e-12f)) > NMS_THRES;
}

// ---------------------------------------------------------------------------
// Kernel B: stable descending sort by conf (key = conf_bits<<13 | (8191-idx)),
// then gather sorted corner/area/conf/c5 SoA + valid bit-words.
// Validity (conf > YOLO_THRES) is a PREFIX of the sorted order.
// ---------------------------------------------------------------------------
__global__ __launch_bounds__(1024) void sort_boxes(
    const float* __restrict__ boxes,
    float* __restrict__ sx1, float* __restrict__ sy1,
    float* __restrict__ sx2, float* __restrict__ sy2,
    float* __restrict__ sarea, float* __restrict__ sconf, float* __restrict__ sc5,
    unsigned long long* __restrict__ Vw) {
    __shared__ unsigned long long keys[SORT_N];
    const int tid = threadIdx.x;

#pragma unroll
    for (int s = 0; s < SORT_N / 1024; ++s) {
        int p = tid + s * 1024;
        unsigned long long key = 0ull;
        if (p < M_BOXES) {
            unsigned int bits = __float_as_uint(boxes[p * 6 + 4]);
            key = ((unsigned long long)bits << 13) | (unsigned long long)(8191 - p);
        }
        keys[p] = key;
    }
    for (int k = 2; k <= SORT_N; k <<= 1) {
        for (int j = k >> 1; j > 0; j >>= 1) {
            __syncthreads();
#pragma unroll
            for (int s = 0; s < SORT_N / 2048; ++s) {   // 4096 pairs / 1024 threads
                int q = tid + s * 1024;
                int i = ((q & ~(j - 1)) << 1) | (q & (j - 1));
                int p2 = i | j;
                unsigned long long a = keys[i], b = keys[p2];
                bool up = ((i & k) == 0);
                if ((a < b) == up) { keys[i] = b; keys[p2] = a; }  // descending overall
            }
        }
    }
    __syncthreads();
#pragma unroll
    for (int s = 0; s < SORT_N / 1024; ++s) {
        int p = tid + s * 1024;
        bool validp = false;
        if (p < M_BOXES) {
            int idx = 8191 - (int)(keys[p] & 0x1FFFull);
            const float* b6 = boxes + idx * 6;
            float x = b6[0], y = b6[1], wd = b6[2], ht = b6[3];
            float conf = b6[4], c5 = b6[5];
            sx1[p] = x - wd * 0.5f;
            sx2[p] = x + wd * 0.5f;
            sy1[p] = y - ht * 0.5f;
            sy2[p] = y + ht * 0.5f;
            sarea[p] = wd * ht;
            sconf[p] = conf;
            sc5[p] = c5;
            validp = conf > YOLO_THRES;
        }
        unsigned long long bits = __ballot(validp);
        int word = (tid >> 6) + s * 16;
        if ((tid & 63) == 0 && word < NWORDS) Vw[word] = bits;
    }
}

// ---------------------------------------------------------------------------
// Mega kernel: role-split by blockIdx.
//  [0, MB_BLOCKS)                     : build suppression mask rows (1 wave/row)
//  [MB_BLOCKS, +P_BLOCKS)             : p_loss
//  [.., +R_BLOCKS)                    : r_loss
//  [.., +B_BLOCKS)                    : b_loss + b_cnt
// mask[row][w] bit j = (IoU(row, w*64+j) > thres) && (w*64+j > row)
// Only valid rows (never-kept rows are never read) and only words with
// Vw[w] != 0 (validity is a prefix -> early break).
// ---------------------------------------------------------------------------
__global__ __launch_bounds__(256) void mega_kernel(
    const float* __restrict__ img, const float* __restrict__ p0,
    const float* __restrict__ p1, const float* __restrict__ p2,
    const float* __restrict__ probs, const float* __restrict__ boxes,
    const float* __restrict__ sx1, const float* __restrict__ sy1,
    const float* __restrict__ sx2, const float* __restrict__ sy2,
    const float* __restrict__ sarea, const unsigned long long* __restrict__ Vw,
    unsigned long long* __restrict__ mask, float* __restrict__ acc) {
    __shared__ float fred[8];
    const int tid = threadIdx.x, lane = tid & 63, wid = tid >> 6;
    const int bid = blockIdx.x;

    if (bid < MB_BLOCKS) {
        int row = bid * 4 + wid;
        if (!((Vw[row >> 6] >> (row & 63)) & 1ull)) return;  // invalid: never kept
        float rx1 = sx1[row], ry1 = sy1[row], rx2 = sx2[row], ry2 = sy2[row];
        float ra = sarea[row];
        unsigned long long* mrow = mask + (size_t)row * NWORDS;
        for (int w = row >> 6; w < NWORDS; ++w) {
            if (Vw[w] == 0ull) break;   // prefix property: rest are all-invalid
            int j = w * 64 + lane;
            bool pred = (j > row) &&
                        iou_gt(rx1, ry1, rx2, ry2, ra,
                               sx1[j], sy1[j], sx2[j], sy2[j], sarea[j]);
            unsigned long long bits = __ballot(pred);
            if (lane == 0) mrow[w] = bits;
        }
        return;
    } else if (bid < MB_BLOCKS + P_BLOCKS) {
        int e = (bid - MB_BLOCKS) * 256 + tid;
        float local = 0.0f;
        if (e < P_ELEMS) {
            float v = img[e];
            int c = e / 250000;
            int rem = e - c * 250000;
            int y = rem / 500;
            int x = rem - y * 500;
            if (x >= 50 && x < 450) {
                int px = x - 50;
                if (y >= 75 && y < 125)       v += p0[c * 20000 + (y - 75) * 400 + px];
                else if (y >= 225 && y < 275) v += p1[c * 20000 + (y - 225) * 400 + px];
                else if (y >= 375 && y < 425) v += p2[c * 20000 + (y - 375) * 400 + px];
            }
            local = fmaxf(-v, 0.0f) + fmaxf(v - 1.0f, 0.0f);
        }
        local = wave_sum(local);
        if (lane == 0) fred[wid] = local;
        __syncthreads();
        if (tid == 0) atomicAdd(&acc[0], fred[0] + fred[1] + fred[2] + fred[3]);
    } else if (bid < MB_BLOCKS + P_BLOCKS + R_BLOCKS) {
        int row = (bid - MB_BLOCKS - P_BLOCKS) * 4 + wid;
        const float* pr = probs + row * 81;
        float m = pr[lane];                          // cols 0..63
        if (lane < 16) m = fmaxf(m, pr[64 + lane]);  // cols 64..79 (col 80 excluded)
        m = wave_max(m);
        float t = 0.0f;
        if (lane == 0 && m > RCNN_THRES) {
            float bp = pr[80];
            float cl = fminf(fmaxf((m - RCNN_THRES) * (1.0f / (0.3f - RCNN_THRES)), 0.0f), 1.0f);
            t = -logf(bp + 0.001f) - cl * logf(1.0f - m + 0.001f);
        }
        if (lane == 0) fred[wid] = t;
        __syncthreads();
        if (tid == 0) atomicAdd(&acc[1], fred[0] + fred[1] + fred[2] + fred[3]);
    } else {
        int i = (bid - MB_BLOCKS - P_BLOCKS - R_BLOCKS) * 256 + tid;
        float l = 0.0f, cnt = 0.0f;
        if (i < M_BOXES) {
            float conf = boxes[i * 6 + 4];
            if (conf > YOLO_THRES) {
                float c5 = boxes[i * 6 + 5];
                l = box_loss_term(c5, conf);
                cnt = 1.0f;
            }
        }
        l = wave_sum(l);
        cnt = wave_sum(cnt);
        if (lane == 0) { fred[wid] = l; fred[4 + wid] = cnt; }
        __syncthreads();
        if (tid == 0) {
            atomicAdd(&acc[2], fred[0] + fred[1] + fred[2] + fred[3]);
            atomicAdd(&acc[3], fred[4] + fred[5] + fred[6] + fred[7]);
        }
    }
}

// ---------------------------------------------------------------------------
// Walk kernel: single wave. Suppression state lives in registers:
// lane l holds sup-word l (sup0) and sup-word 64+l (sup1).
// Per kept box: 1 broadcast load (dependent) + 2 per-lane loads (independent).
// Then b_nms loss + final combine.
// ---------------------------------------------------------------------------
__global__ __launch_bounds__(64) void nms_walk(
    const float* __restrict__ acc, const unsigned long long* __restrict__ Vw,
    const unsigned long long* __restrict__ mask,
    const float* __restrict__ sconf, const float* __restrict__ sc5,
    float* __restrict__ out) {
    const int lane = threadIdx.x;
    unsigned long long sup0 = 0ull, sup1 = 0ull;   // suppression words lane, 64+lane
    unsigned long long kw0 = 0ull, kw1 = 0ull;     // keep words lane, 64+lane

    for (int w = 0; w < NWORDS; ++w) {
        unsigned long long supw = (w < 64) ? __shfl(sup0, w) : __shfl(sup1, w - 64);
        unsigned long long cur = Vw[w] & ~supw;    // uniform across the wave
        unsigned long long rem = cur;
        while (rem) {
            int t = __builtin_ctzll(rem);
            const unsigned long long* mrow = mask + (size_t)(w * 64 + t) * NWORDS;
            unsigned long long m = mrow[w];        // broadcast load (dependent chain)
            if (lane > w)      sup0 |= mrow[lane];       // independent loads
            if (64 + lane > w) sup1 |= mrow[64 + lane];
            cur &= ~m;
            rem &= ~m;
            rem &= rem - 1;  // clear bit t (m never contains bits <= t)
        }
        if (w < 64) { if (lane == w) kw0 = cur; }
        else        { if (lane == w - 64) kw1 = cur; }
    }

    // b_nms_loss / b_nms_cnt over kept boxes (keep words broadcast via shfl)
    float nl = 0.0f, nc = 0.0f;
    for (int w = 0; w < NWORDS; ++w) {
        unsigned long long kwv = (w < 64) ? __shfl(kw0, w) : __shfl(kw1, w - 64);
        if ((kwv >> lane) & 1ull) {
            int p = w * 64 + lane;
            nl += box_loss_term(sc5[p], sconf[p]);
            nc += 1.0f;
        }
    }
    nl = wave_sum(nl);
    nc = wave_sum(nc);
    if (lane == 0) {
        float p_loss = acc[0], r_loss = acc[1], b_loss = acc[2], b_cnt = acc[3];
        float yolo = b_loss + nl * (b_cnt / fmaxf(nc, 1.0f));
        out[0] = r_loss * 0.8f + yolo + p_loss;
    }
}

// ---------------------------------------------------------------------------
extern "C" void kernel_launch(void* const* d_in, const int* in_sizes, int n_in,
                              void* d_out, int out_size, void* d_ws, size_t ws_size,
                              hipStream_t stream) {
    const float* img   = (const float*)d_in[0];
    const float* p0    = (const float*)d_in[1];
    const float* p1    = (const float*)d_in[2];
    const float* p2    = (const float*)d_in[3];
    const float* probs = (const float*)d_in[4];
    const float* boxes = (const float*)d_in[5];
    float* out = (float*)d_out;

    char* ws = (char*)d_ws;
    float* acc = (float*)ws;                                  // 8 floats @ 0
    unsigned long long* Vw = (unsigned long long*)(ws + 64);  // 96 words
    float* sx1 = (float*)(ws + 1024);
    float* sy1 = sx1 + M_BOXES;
    float* sx2 = sy1 + M_BOXES;
    float* sy2 = sx2 + M_BOXES;
    float* sarea = sy2 + M_BOXES;
    float* sconf = sarea + M_BOXES;
    float* sc5 = sconf + M_BOXES;
    // mask: 6144 rows x 96 words x 8 B = 4.72 MB @ offset 173056 (8-aligned)
    unsigned long long* mask = (unsigned long long*)(ws + 173056);

    hipMemsetAsync(acc, 0, 64, stream);
    sort_boxes<<<1, 1024, 0, stream>>>(boxes, sx1, sy1, sx2, sy2, sarea, sconf, sc5, Vw);
    mega_kernel<<<MB_BLOCKS + P_BLOCKS + R_BLOCKS + B_BLOCKS, 256, 0, stream>>>(
        img, p0, p1, p2, probs, boxes, sx1, sy1, sx2, sy2, sarea, Vw, mask, acc);
    nms_walk<<<1, 64, 0, stream>>>(acc, Vw, mask, sconf, sc5, out);
}